// Round 1
// baseline (707.427 us; speedup 1.0000x reference)
//
#include <hip/hip_runtime.h>
#include <hip/hip_bf16.h>

#define BN_  16
#define CH   1024
#define MIDC 512
#define NPIX 2304   // 48*48

typedef __bf16 bf16x8 __attribute__((ext_vector_type(8)));
typedef float  f32x4  __attribute__((ext_vector_type(4)));

typedef __attribute__((address_space(1))) void void_g;
typedef __attribute__((address_space(3))) void void_l;

__device__ __forceinline__ void gll16(const void* g, void* l) {
  __builtin_amdgcn_global_load_lds((const void_g*)g, (void_l*)l, 16, 0, 0);
}

// ---------------------------------------------------------------------------
// BT-form GEMM: C[m][n] = sum_k A[m][k] * B[n][k], A/B row-major bf16 [*, K].
// 128x128 tile, BK=32, 256 threads (4 waves, 2x2 wave grid, 64x64 per wave,
// 4x4 frags of 16x16x32 MFMA). m97 structure: global_load_lds(16B) staging,
// linear LDS [128][32], ds_read_b128 fragments.
// EPI: 0=none(bf16) 1=per-col scale/shift+relu(bf16) 2=per-row bias(bf16)
//      3=scalar scale(bf16) 4=per-row bias + residual, fp32 out
// ---------------------------------------------------------------------------
template<int EPI>
__global__ __launch_bounds__(256)
void gemm_bt(const __hip_bfloat16* __restrict__ Ag, int lda, long sA,
             const __hip_bfloat16* __restrict__ Bg, int ldb, long sB,
             void* __restrict__ Cg, int ldc, long sC,
             int K,
             const float* __restrict__ e0, const float* __restrict__ e1,
             const float* __restrict__ resid, long sR, float fscale)
{
  __shared__ __align__(16) __hip_bfloat16 lA[128 * 32];
  __shared__ __align__(16) __hip_bfloat16 lB[128 * 32];
  const int tid  = threadIdx.x;
  const int lane = tid & 63;
  const int wave = tid >> 6;
  const int bz   = blockIdx.z;
  const int m0   = blockIdx.x * 128;
  const int n0   = blockIdx.y * 128;

  // staging: thread t covers LDS elems [t*8, t*8+8)  (row = t>>2, kchunk = (t&3)*8)
  const __hip_bfloat16* Ab = Ag + (long)bz * sA + (long)(m0 + (tid >> 2)) * lda + (tid & 3) * 8;
  const __hip_bfloat16* Bb = Bg + (long)bz * sB + (long)(n0 + (tid >> 2)) * ldb + (tid & 3) * 8;
  __hip_bfloat16* lAw = lA + wave * 512;   // wave-uniform LDS dest base
  __hip_bfloat16* lBw = lB + wave * 512;
  const long a64 = (long)64 * lda, b64r = (long)64 * ldb;

  const int wr = wave >> 1, wc = wave & 1;
  const int fr  = lane & 15;
  const int fko = (lane >> 4) * 8;

  f32x4 acc[4][4] = {};

  for (int k0 = 0; k0 < K; k0 += 32) {
    gll16(Ab + k0,        lAw);
    gll16(Ab + k0 + a64,  lAw + 2048);
    gll16(Bb + k0,        lBw);
    gll16(Bb + k0 + b64r, lBw + 2048);
    __syncthreads();   // compiler drains vmcnt before s_barrier
    bf16x8 af[4], bfv[4];
#pragma unroll
    for (int i = 0; i < 4; ++i)
      af[i] = *(const bf16x8*)(lA + (wr * 64 + i * 16 + fr) * 32 + fko);
#pragma unroll
    for (int i = 0; i < 4; ++i)
      bfv[i] = *(const bf16x8*)(lB + (wc * 64 + i * 16 + fr) * 32 + fko);
#pragma unroll
    for (int mi = 0; mi < 4; ++mi)
#pragma unroll
      for (int ni = 0; ni < 4; ++ni)
        acc[mi][ni] = __builtin_amdgcn_mfma_f32_16x16x32_bf16(af[mi], bfv[ni], acc[mi][ni], 0, 0, 0);
    __syncthreads();
  }

  // C/D layout (m89-verified): col = lane&15, row = (lane>>4)*4 + reg
  const int rbase = m0 + wr * 64 + (lane >> 4) * 4;
  const int cbase = n0 + wc * 64 + fr;
  if constexpr (EPI == 4) {
    float* Cb = (float*)Cg + (long)bz * sC;
    const float* Rb = resid + (long)bz * sR;
#pragma unroll
    for (int mi = 0; mi < 4; ++mi) {
#pragma unroll
      for (int r = 0; r < 4; ++r) {
        const int row = rbase + mi * 16 + r;
        const float bias = e0[row];
#pragma unroll
        for (int ni = 0; ni < 4; ++ni) {
          const long idx = (long)row * ldc + cbase + ni * 16;
          Cb[idx] = acc[mi][ni][r] + bias + Rb[idx];
        }
      }
    }
  } else {
    __hip_bfloat16* Cb = (__hip_bfloat16*)Cg + (long)bz * sC;
#pragma unroll
    for (int mi = 0; mi < 4; ++mi) {
#pragma unroll
      for (int r = 0; r < 4; ++r) {
        const int row = rbase + mi * 16 + r;
#pragma unroll
        for (int ni = 0; ni < 4; ++ni) {
          const int col = cbase + ni * 16;
          float v = acc[mi][ni][r];
          if constexpr (EPI == 1) { v = fmaxf(v * e0[col] + e1[col], 0.f); }
          if constexpr (EPI == 2) { v += e0[row]; }
          if constexpr (EPI == 3) { v *= fscale; }
          Cb[(long)row * ldc + col] = __float2bfloat16(v);
        }
      }
    }
  }
}

// ---------------------------------------------------------------------------
// Row softmax in-place on bf16 logits, one 256-thread block per row of 2304.
// ---------------------------------------------------------------------------
__global__ __launch_bounds__(256)
void softmax_rows(__hip_bfloat16* __restrict__ z)
{
  const long row = blockIdx.x;
  __hip_bfloat16* p = z + row * NPIX;
  const int t = threadIdx.x;
  const int lane = t & 63, wave = t >> 6;

  float v[9];
  bf16x8 pk = *(const bf16x8*)(p + t * 8);
#pragma unroll
  for (int i = 0; i < 8; ++i) v[i] = (float)pk[i];
  v[8] = __bfloat162float(p[2048 + t]);

  float mx = v[0];
#pragma unroll
  for (int i = 1; i < 9; ++i) mx = fmaxf(mx, v[i]);
#pragma unroll
  for (int o = 32; o > 0; o >>= 1) mx = fmaxf(mx, __shfl_xor(mx, o));
  __shared__ float redm[4], reds[4];
  if (lane == 0) redm[wave] = mx;
  __syncthreads();
  mx = fmaxf(fmaxf(redm[0], redm[1]), fmaxf(redm[2], redm[3]));

  float s = 0.f;
#pragma unroll
  for (int i = 0; i < 9; ++i) { v[i] = __expf(v[i] - mx); s += v[i]; }
#pragma unroll
  for (int o = 32; o > 0; o >>= 1) s += __shfl_xor(s, o);
  if (lane == 0) reds[wave] = s;
  __syncthreads();
  s = reds[0] + reds[1] + reds[2] + reds[3];
  const float inv = 1.f / s;

  bf16x8 ok;
#pragma unroll
  for (int i = 0; i < 8; ++i) ok[i] = (__bf16)(v[i] * inv);
  *(bf16x8*)(p + t * 8) = ok;
  p[2048 + t] = __float2bfloat16(v[8] * inv);
}

// ---------------------------------------------------------------------------
// x[b][c][n] f32  ->  xt[b][n][c] bf16   (64x64 LDS tile transpose)
// ---------------------------------------------------------------------------
__global__ __launch_bounds__(256)
void transpose_cvt(const float* __restrict__ x, __hip_bfloat16* __restrict__ xt)
{
  __shared__ float tile[64 * 65];
  const int n0 = blockIdx.x * 64, c0 = blockIdx.y * 64;
  const long bo = (long)blockIdx.z * CH * NPIX;
  const int t = threadIdx.x;
#pragma unroll
  for (int i = 0; i < 16; ++i) {
    const int idx = i * 256 + t;
    const int cl = idx >> 6, nl = idx & 63;
    tile[cl * 65 + nl] = x[bo + (long)(c0 + cl) * NPIX + n0 + nl];
  }
  __syncthreads();
#pragma unroll
  for (int i = 0; i < 16; ++i) {
    const int idx = i * 256 + t;
    const int nl = idx >> 6, cl = idx & 63;
    xt[bo + (long)(n0 + nl) * CH + c0 + cl] = __float2bfloat16(tile[cl * 65 + nl]);
  }
}

__global__ __launch_bounds__(256)
void cvt_bf16(const float* __restrict__ s, __hip_bfloat16* __restrict__ d, int n)
{
  const int i = blockIdx.x * 256 + threadIdx.x;
  if (i < n) d[i] = __float2bfloat16(s[i]);
}

// Fold conv-bias + BN into per-channel scale/shift:  out = relu(acc*sc + sh)
__global__ void prep_scales(const float* bf_, const float* gf, const float* bef,
                            const float* mf, const float* vf,
                            const float* bg_, const float* gg, const float* beg,
                            const float* mg, const float* vg,
                            float* sc, float* sh)
{
  const int r = blockIdx.x * 256 + threadIdx.x;
  if (r >= 1024) return;
  int j; const float *b, *g, *be, *m, *vv;
  if (r < 512) { b = bf_; g = gf; be = bef; m = mf; vv = vf; j = r; }
  else         { b = bg_; g = gg; be = beg; m = mg; vv = vg; j = r - 512; }
  const float inv = g[j] / sqrtf(vv[j] + 1e-5f);
  sc[r] = inv;
  sh[r] = (b[j] - m[j]) * inv + be[j];
}

extern "C" void kernel_launch(void* const* d_in, const int* in_sizes, int n_in,
                              void* d_out, int out_size, void* d_ws, size_t ws_size,
                              hipStream_t stream)
{
  const float* x     = (const float*)d_in[0];
  const float* Wf    = (const float*)d_in[1];
  const float* bf_   = (const float*)d_in[2];
  const float* gf    = (const float*)d_in[3];
  const float* betaf = (const float*)d_in[4];
  const float* mf    = (const float*)d_in[5];
  const float* vf    = (const float*)d_in[6];
  const float* Wg    = (const float*)d_in[7];
  const float* bg_   = (const float*)d_in[8];
  const float* gg    = (const float*)d_in[9];
  const float* betag = (const float*)d_in[10];
  const float* mg    = (const float*)d_in[11];
  const float* vg    = (const float*)d_in[12];
  const float* Wh    = (const float*)d_in[13];
  const float* bh    = (const float*)d_in[14];
  const float* Wv    = (const float*)d_in[15];
  const float* bv    = (const float*)d_in[16];
  float* out = (float*)d_out;
  (void)in_sizes; (void)n_in; (void)out_size; (void)ws_size;

  char* ws = (char*)d_ws;
  size_t off = 0;
  auto take = [&](size_t bytes) -> char* {
    char* p = ws + off;
    off += (bytes + 255) & ~(size_t)255;
    return p;
  };
  __hip_bfloat16* xt   = (__hip_bfloat16*)take((size_t)BN_ * NPIX * CH * 2);    // 75.5 MB
  __hip_bfloat16* fgT  = (__hip_bfloat16*)take((size_t)BN_ * NPIX * 1024 * 2);  // 75.5 MB
  __hip_bfloat16* hbuf = (__hip_bfloat16*)take((size_t)BN_ * MIDC * NPIX * 2);  // 37.7 MB
  __hip_bfloat16* om   = (__hip_bfloat16*)take((size_t)BN_ * NPIX * MIDC * 2);  // 37.7 MB
  __hip_bfloat16* zat  = (__hip_bfloat16*)take((size_t)BN_ * NPIX * NPIX * 2);  // 169.9 MB
  __hip_bfloat16* Wfgb = (__hip_bfloat16*)take((size_t)1024 * CH * 2);
  __hip_bfloat16* Whb  = (__hip_bfloat16*)take((size_t)MIDC * CH * 2);
  __hip_bfloat16* Wvb  = (__hip_bfloat16*)take((size_t)CH * MIDC * 2);
  float* scfg = (float*)take(1024 * 4);
  float* shfg = (float*)take(1024 * 4);

  prep_scales<<<dim3(4), dim3(256), 0, stream>>>(bf_, gf, betaf, mf, vf,
                                                 bg_, gg, betag, mg, vg, scfg, shfg);
  cvt_bf16<<<dim3(2048), dim3(256), 0, stream>>>(Wf, Wfgb,              512 * 1024);
  cvt_bf16<<<dim3(2048), dim3(256), 0, stream>>>(Wg, Wfgb + 512 * 1024, 512 * 1024);
  cvt_bf16<<<dim3(2048), dim3(256), 0, stream>>>(Wh, Whb,               512 * 1024);
  cvt_bf16<<<dim3(2048), dim3(256), 0, stream>>>(Wv, Wvb,               1024 * 512);
  transpose_cvt<<<dim3(36, 16, BN_), dim3(256), 0, stream>>>(x, xt);

  // fgT[b][n][r] = sum_c xt[b][n][c] * Wfg[r][c]   (+ fused BN+ReLU per col r)
  gemm_bt<1><<<dim3(18, 8, BN_), dim3(256), 0, stream>>>(
      xt, CH, (long)NPIX * CH, Wfgb, CH, 0L,
      fgT, 1024, (long)NPIX * 1024, CH,
      scfg, shfg, nullptr, 0L, 0.f);

  // h[b][m][n] = sum_c Wh[m][c] * xt[b][n][c]  (+ bias per row m)
  gemm_bt<2><<<dim3(4, 18, BN_), dim3(256), 0, stream>>>(
      Whb, CH, 0L, xt, CH, (long)NPIX * CH,
      hbuf, NPIX, (long)MIDC * NPIX, CH,
      bh, nullptr, nullptr, 0L, 0.f);

  // z[b][i][j] = (sum_m fT[i][m] * gT[j][m]) * 512^-0.5   -> bf16 logits
  gemm_bt<3><<<dim3(18, 18, BN_), dim3(256), 0, stream>>>(
      fgT, 1024, (long)NPIX * 1024, fgT + 512, 1024, (long)NPIX * 1024,
      zat, NPIX, (long)NPIX * NPIX, MIDC,
      nullptr, nullptr, nullptr, 0L, 0.044194173824159216f);

  softmax_rows<<<dim3(BN_ * NPIX), dim3(256), 0, stream>>>(zat);

  // om[b][i][o] = sum_j attn[i][j] * h[o][j]
  gemm_bt<0><<<dim3(18, 4, BN_), dim3(256), 0, stream>>>(
      zat, NPIX, (long)NPIX * NPIX, hbuf, NPIX, (long)MIDC * NPIX,
      om, MIDC, (long)NPIX * MIDC, NPIX,
      nullptr, nullptr, nullptr, 0L, 0.f);

  // out[b][c][n] = sum_o Wv[c][o] * om[b][n][o] + bv[c] + x[b][c][n]
  gemm_bt<4><<<dim3(8, 18, BN_), dim3(256), 0, stream>>>(
      Wvb, MIDC, 0L, om, MIDC, (long)NPIX * MIDC,
      out, NPIX, (long)CH * NPIX, MIDC,
      bv, nullptr, x, (long)CH * NPIX, 0.f);
}

// Round 2
// 604.870 us; speedup vs baseline: 1.1696x; 1.1696x over previous
//
#include <hip/hip_runtime.h>
#include <hip/hip_bf16.h>

#define BN_  16
#define CH   1024
#define MIDC 512
#define NPIX 2304   // 48*48

typedef __bf16 bf16x8 __attribute__((ext_vector_type(8)));
typedef __bf16 bf16x4 __attribute__((ext_vector_type(4)));
typedef float  f32x4  __attribute__((ext_vector_type(4)));

typedef __attribute__((address_space(1))) void void_g;
typedef __attribute__((address_space(3))) void void_l;

__device__ __forceinline__ void gll16(const void* g, void* l) {
  __builtin_amdgcn_global_load_lds((const void_g*)g, (void_l*)l, 16, 0, 0);
}

// ---------------------------------------------------------------------------
// BT-form GEMM: C[m][n] = sum_k A[m][k] * B[n][k], A/B row-major bf16 [*, K].
// 128x128 tile, BK=64, 256 threads (4 waves, 2x2 wave grid, 64x64 per wave,
// 4x4 frags of 16x16x32 MFMA, 2 K-slices per LDS tile).
// LDS: [128][64] per matrix with chunk-XOR swizzle (chunk ^= row&7, 8-elem
// chunks) applied via pre-swizzled GLOBAL source (gll16 dest stays linear)
// and on the ds_read side -> conflict-free b128 reads (8 bank-groups).
// Grid is XCD-swizzled: wg = (L%8)*(nwg/8) + L/8 (all launches nwg%8==0).
// EPI: 0=none(bf16) 1=per-col scale/shift+relu(bf16) 2=per-row bias(bf16)
//      3=scalar scale(bf16) 4=per-row bias + residual, fp32 out
// ---------------------------------------------------------------------------
template<int EPI>
__global__ __launch_bounds__(256)
void gemm_bt(const __hip_bfloat16* __restrict__ Ag, int lda, long sA,
             const __hip_bfloat16* __restrict__ Bg, int ldb, long sB,
             void* __restrict__ Cg, int ldc, long sC,
             int K,
             const float* __restrict__ e0, const float* __restrict__ e1,
             const float* __restrict__ resid, long sR, float fscale)
{
  __shared__ __align__(16) __hip_bfloat16 lA[128 * 64];
  __shared__ __align__(16) __hip_bfloat16 lB[128 * 64];
  const int tid  = threadIdx.x;
  const int lane = tid & 63;
  const int wave = tid >> 6;

  // XCD-aware bijective remap (nwg % 8 == 0 for every launch below)
  const int gx = gridDim.x, gy = gridDim.y;
  const int nwg = gx * gy * gridDim.z;
  const int L  = blockIdx.x + gx * (blockIdx.y + gy * blockIdx.z);
  const int wg = (L & 7) * (nwg >> 3) + (L >> 3);
  const int pb = gx * gy;
  const int bz = wg / pb;
  const int rem = wg - bz * pb;
  const int m0 = (rem % gx) * 128;
  const int n0 = (rem / gx) * 128;

  // staging: thread t covers LDS elems [c*2048 + t*8, +8) for call c=0..3
  // LDS (row, chunk) holds logical chunk (chunk ^ (row&7))  [chunk = 8 elems]
  const int srow = tid >> 3;                     // 0..31 (+32 per call)
  const int schk = (tid & 7) ^ (srow & 7);       // pre-swizzled source chunk
  const __hip_bfloat16* Ab = Ag + (long)bz * sA + (long)(m0 + srow) * lda + schk * 8;
  const __hip_bfloat16* Bb = Bg + (long)bz * sB + (long)(n0 + srow) * ldb + schk * 8;
  __hip_bfloat16* lAw = lA + wave * 512;         // wave-uniform LDS dest base
  __hip_bfloat16* lBw = lB + wave * 512;

  const int wr = wave >> 1, wc = wave & 1;
  const int fr = lane & 15;
  const int fc = lane >> 4;                      // k-chunk within slice (0..3)

  f32x4 acc[4][4] = {};

  for (int k0 = 0; k0 < K; k0 += 64) {
#pragma unroll
    for (int c = 0; c < 4; ++c) {
      gll16(Ab + k0 + (long)c * 32 * lda, lAw + c * 2048);
      gll16(Bb + k0 + (long)c * 32 * ldb, lBw + c * 2048);
    }
    __syncthreads();   // compiler drains vmcnt before s_barrier
#pragma unroll
    for (int kk = 0; kk < 2; ++kk) {
      bf16x8 af[4], bfv[4];
#pragma unroll
      for (int i = 0; i < 4; ++i) {
        const int ra = wr * 64 + i * 16 + fr;
        af[i]  = *(const bf16x8*)(lA + ra * 64 + (((kk * 4 + fc) ^ (fr & 7)) * 8));
        const int rb = wc * 64 + i * 16 + fr;
        bfv[i] = *(const bf16x8*)(lB + rb * 64 + (((kk * 4 + fc) ^ (fr & 7)) * 8));
      }
#pragma unroll
      for (int mi = 0; mi < 4; ++mi)
#pragma unroll
        for (int ni = 0; ni < 4; ++ni)
          acc[mi][ni] = __builtin_amdgcn_mfma_f32_16x16x32_bf16(af[mi], bfv[ni], acc[mi][ni], 0, 0, 0);
    }
    __syncthreads();
  }

  // C/D layout (m89-verified): col = lane&15, row = (lane>>4)*4 + reg
  const int rbase = m0 + wr * 64 + (lane >> 4) * 4;
  const int cbase = n0 + wc * 64 + fr;
  if constexpr (EPI == 4) {
    float* Cb = (float*)Cg + (long)bz * sC;
    const float* Rb = resid + (long)bz * sR;
#pragma unroll
    for (int mi = 0; mi < 4; ++mi) {
#pragma unroll
      for (int r = 0; r < 4; ++r) {
        const int row = rbase + mi * 16 + r;
        const float bias = e0[row];
#pragma unroll
        for (int ni = 0; ni < 4; ++ni) {
          const long idx = (long)row * ldc + cbase + ni * 16;
          Cb[idx] = acc[mi][ni][r] + bias + Rb[idx];
        }
      }
    }
  } else {
    __hip_bfloat16* Cb = (__hip_bfloat16*)Cg + (long)bz * sC;
#pragma unroll
    for (int mi = 0; mi < 4; ++mi) {
#pragma unroll
      for (int r = 0; r < 4; ++r) {
        const int row = rbase + mi * 16 + r;
#pragma unroll
        for (int ni = 0; ni < 4; ++ni) {
          const int col = cbase + ni * 16;
          float v = acc[mi][ni][r];
          if constexpr (EPI == 1) { v = fmaxf(v * e0[col] + e1[col], 0.f); }
          if constexpr (EPI == 2) { v += e0[row]; }
          if constexpr (EPI == 3) { v *= fscale; }
          Cb[(long)row * ldc + col] = __float2bfloat16(v);
        }
      }
    }
  }
}

// ---------------------------------------------------------------------------
// Row softmax in-place on bf16 logits, one 256-thread block per row of 2304.
// ---------------------------------------------------------------------------
__global__ __launch_bounds__(256)
void softmax_rows(__hip_bfloat16* __restrict__ z)
{
  const long row = blockIdx.x;
  __hip_bfloat16* p = z + row * NPIX;
  const int t = threadIdx.x;
  const int lane = t & 63, wave = t >> 6;

  float v[9];
  bf16x8 pk = *(const bf16x8*)(p + t * 8);
#pragma unroll
  for (int i = 0; i < 8; ++i) v[i] = (float)pk[i];
  v[8] = __bfloat162float(p[2048 + t]);

  float mx = v[0];
#pragma unroll
  for (int i = 1; i < 9; ++i) mx = fmaxf(mx, v[i]);
#pragma unroll
  for (int o = 32; o > 0; o >>= 1) mx = fmaxf(mx, __shfl_xor(mx, o));
  __shared__ float redm[4], reds[4];
  if (lane == 0) redm[wave] = mx;
  __syncthreads();
  mx = fmaxf(fmaxf(redm[0], redm[1]), fmaxf(redm[2], redm[3]));

  float s = 0.f;
#pragma unroll
  for (int i = 0; i < 9; ++i) { v[i] = __expf(v[i] - mx); s += v[i]; }
#pragma unroll
  for (int o = 32; o > 0; o >>= 1) s += __shfl_xor(s, o);
  if (lane == 0) reds[wave] = s;
  __syncthreads();
  s = reds[0] + reds[1] + reds[2] + reds[3];
  const float inv = 1.f / s;

  bf16x8 ok;
#pragma unroll
  for (int i = 0; i < 8; ++i) ok[i] = (__bf16)(v[i] * inv);
  *(bf16x8*)(p + t * 8) = ok;
  p[2048 + t] = __float2bfloat16(v[8] * inv);
}

// ---------------------------------------------------------------------------
// x[b][c][n] f32  ->  xt[b][n][c] bf16   (64x64 LDS tile transpose)
// ---------------------------------------------------------------------------
__global__ __launch_bounds__(256)
void transpose_cvt(const float* __restrict__ x, __hip_bfloat16* __restrict__ xt)
{
  __shared__ float tile[64 * 65];
  const int n0 = blockIdx.x * 64, c0 = blockIdx.y * 64;
  const long bo = (long)blockIdx.z * CH * NPIX;
  const int t = threadIdx.x;
#pragma unroll
  for (int i = 0; i < 16; ++i) {
    const int idx = i * 256 + t;
    const int cl = idx >> 6, nl = idx & 63;
    tile[cl * 65 + nl] = x[bo + (long)(c0 + cl) * NPIX + n0 + nl];
  }
  __syncthreads();
#pragma unroll
  for (int i = 0; i < 16; ++i) {
    const int idx = i * 256 + t;
    const int nl = idx >> 6, cl = idx & 63;
    xt[bo + (long)(n0 + nl) * CH + c0 + cl] = __float2bfloat16(tile[cl * 65 + nl]);
  }
}

// All four weights are 512*1024 = 524288 elems; one launch, float4 -> bf16x4.
__global__ __launch_bounds__(256)
void cvt4(const float* __restrict__ a, const float* __restrict__ b,
          const float* __restrict__ c, const float* __restrict__ d,
          __hip_bfloat16* oa, __hip_bfloat16* ob,
          __hip_bfloat16* oc, __hip_bfloat16* od)
{
  const int i = (blockIdx.x * 256 + threadIdx.x) * 4;   // 512 blocks covers 524288
  const float* s; __hip_bfloat16* o;
  switch (blockIdx.y) {
    case 0:  s = a; o = oa; break;
    case 1:  s = b; o = ob; break;
    case 2:  s = c; o = oc; break;
    default: s = d; o = od; break;
  }
  const float4 v = *(const float4*)(s + i);
  bf16x4 w;
  w[0] = (__bf16)v.x; w[1] = (__bf16)v.y; w[2] = (__bf16)v.z; w[3] = (__bf16)v.w;
  *(bf16x4*)(o + i) = w;
}

// Fold conv-bias + BN into per-channel scale/shift:  out = relu(acc*sc + sh)
__global__ void prep_scales(const float* bf_, const float* gf, const float* bef,
                            const float* mf, const float* vf,
                            const float* bg_, const float* gg, const float* beg,
                            const float* mg, const float* vg,
                            float* sc, float* sh)
{
  const int r = blockIdx.x * 256 + threadIdx.x;
  if (r >= 1024) return;
  int j; const float *b, *g, *be, *m, *vv;
  if (r < 512) { b = bf_; g = gf; be = bef; m = mf; vv = vf; j = r; }
  else         { b = bg_; g = gg; be = beg; m = mg; vv = vg; j = r - 512; }
  const float inv = g[j] / sqrtf(vv[j] + 1e-5f);
  sc[r] = inv;
  sh[r] = (b[j] - m[j]) * inv + be[j];
}

extern "C" void kernel_launch(void* const* d_in, const int* in_sizes, int n_in,
                              void* d_out, int out_size, void* d_ws, size_t ws_size,
                              hipStream_t stream)
{
  const float* x     = (const float*)d_in[0];
  const float* Wf    = (const float*)d_in[1];
  const float* bf_   = (const float*)d_in[2];
  const float* gf    = (const float*)d_in[3];
  const float* betaf = (const float*)d_in[4];
  const float* mf    = (const float*)d_in[5];
  const float* vf    = (const float*)d_in[6];
  const float* Wg    = (const float*)d_in[7];
  const float* bg_   = (const float*)d_in[8];
  const float* gg    = (const float*)d_in[9];
  const float* betag = (const float*)d_in[10];
  const float* mg    = (const float*)d_in[11];
  const float* vg    = (const float*)d_in[12];
  const float* Wh    = (const float*)d_in[13];
  const float* bh    = (const float*)d_in[14];
  const float* Wv    = (const float*)d_in[15];
  const float* bv    = (const float*)d_in[16];
  float* out = (float*)d_out;
  (void)in_sizes; (void)n_in; (void)out_size; (void)ws_size;

  char* ws = (char*)d_ws;
  size_t off = 0;
  auto take = [&](size_t bytes) -> char* {
    char* p = ws + off;
    off += (bytes + 255) & ~(size_t)255;
    return p;
  };
  __hip_bfloat16* xt   = (__hip_bfloat16*)take((size_t)BN_ * NPIX * CH * 2);    // 75.5 MB
  __hip_bfloat16* fgT  = (__hip_bfloat16*)take((size_t)BN_ * NPIX * 1024 * 2);  // 75.5 MB
  __hip_bfloat16* hbuf = (__hip_bfloat16*)take((size_t)BN_ * MIDC * NPIX * 2);  // 37.7 MB
  __hip_bfloat16* om   = (__hip_bfloat16*)take((size_t)BN_ * NPIX * MIDC * 2);  // 37.7 MB
  __hip_bfloat16* zat  = (__hip_bfloat16*)take((size_t)BN_ * NPIX * NPIX * 2);  // 169.9 MB
  __hip_bfloat16* Wfgb = (__hip_bfloat16*)take((size_t)1024 * CH * 2);
  __hip_bfloat16* Whb  = (__hip_bfloat16*)take((size_t)MIDC * CH * 2);
  __hip_bfloat16* Wvb  = (__hip_bfloat16*)take((size_t)CH * MIDC * 2);
  float* scfg = (float*)take(1024 * 4);
  float* shfg = (float*)take(1024 * 4);

  prep_scales<<<dim3(4), dim3(256), 0, stream>>>(bf_, gf, betaf, mf, vf,
                                                 bg_, gg, betag, mg, vg, scfg, shfg);
  cvt4<<<dim3(512, 4), dim3(256), 0, stream>>>(Wf, Wg, Wh, Wv,
                                               Wfgb, Wfgb + 512 * 1024, Whb, Wvb);
  transpose_cvt<<<dim3(36, 16, BN_), dim3(256), 0, stream>>>(x, xt);

  // fgT[b][n][r] = sum_c xt[b][n][c] * Wfg[r][c]   (+ fused BN+ReLU per col r)
  gemm_bt<1><<<dim3(18, 8, BN_), dim3(256), 0, stream>>>(
      xt, CH, (long)NPIX * CH, Wfgb, CH, 0L,
      fgT, 1024, (long)NPIX * 1024, CH,
      scfg, shfg, nullptr, 0L, 0.f);

  // h[b][m][n] = sum_c Wh[m][c] * xt[b][n][c]  (+ bias per row m)
  gemm_bt<2><<<dim3(4, 18, BN_), dim3(256), 0, stream>>>(
      Whb, CH, 0L, xt, CH, (long)NPIX * CH,
      hbuf, NPIX, (long)MIDC * NPIX, CH,
      bh, nullptr, nullptr, 0L, 0.f);

  // z[b][i][j] = (sum_m fT[i][m] * gT[j][m]) * 512^-0.5   -> bf16 logits
  gemm_bt<3><<<dim3(18, 18, BN_), dim3(256), 0, stream>>>(
      fgT, 1024, (long)NPIX * 1024, fgT + 512, 1024, (long)NPIX * 1024,
      zat, NPIX, (long)NPIX * NPIX, MIDC,
      nullptr, nullptr, nullptr, 0L, 0.044194173824159216f);

  softmax_rows<<<dim3(BN_ * NPIX), dim3(256), 0, stream>>>(zat);

  // om[b][i][o] = sum_j attn[i][j] * h[o][j]
  gemm_bt<0><<<dim3(18, 4, BN_), dim3(256), 0, stream>>>(
      zat, NPIX, (long)NPIX * NPIX, hbuf, NPIX, (long)MIDC * NPIX,
      om, MIDC, (long)NPIX * MIDC, NPIX,
      nullptr, nullptr, nullptr, 0L, 0.f);

  // out[b][c][n] = sum_o Wv[c][o] * om[b][n][o] + bv[c] + x[b][c][n]
  gemm_bt<4><<<dim3(8, 18, BN_), dim3(256), 0, stream>>>(
      Wvb, MIDC, 0L, om, MIDC, (long)NPIX * MIDC,
      out, NPIX, (long)CH * NPIX, MIDC,
      bv, nullptr, x, (long)CH * NPIX, 0.f);
}